// Round 4
// baseline (294.128 us; speedup 1.0000x reference)
//
#include <hip/hip_runtime.h>

typedef _Float16 half2v __attribute__((ext_vector_type(2)));
typedef _Float16 half4 __attribute__((ext_vector_type(4)));
typedef _Float16 half8 __attribute__((ext_vector_type(8)));
typedef float floatx4 __attribute__((ext_vector_type(4)));

#define B_   8
#define SE   4096
#define SD   4096
#define D_   128
#define NT   64      // K/V rows per tile
#define NZ   2       // encoder-sequence split factor
#define TILES (SE / NZ / NT)   // 32 tiles per z-half
#define LDB  136
#define LOG2E 1.44269504f

// async 16B global->LDS: per-lane global address, wave-uniform LDS base (+lane*16 by HW)
__device__ __forceinline__ void cp16_async(const _Float16* g, _Float16* l) {
    __builtin_amdgcn_global_load_lds((const __attribute__((address_space(1))) unsigned int*)g,
                                     (__attribute__((address_space(3))) unsigned int*)l, 16, 0, 0);
}

__device__ __forceinline__ float dot2acc(half2v a, half2v b, float c) {
#if __has_builtin(__builtin_amdgcn_fdot2)
    return __builtin_amdgcn_fdot2(a, b, c, false);
#else
    return c + (float)a[0] * (float)b[0] + (float)a[1] * (float)b[1];
#endif
}

// ---------- prep: kc = fp16(b), vT = fp16(b^T); W error-split folded in ----------
__global__ __launch_bounds__(256) void bprep(const float* __restrict__ b,
                                             const float* __restrict__ W,
                                             _Float16* __restrict__ kc,
                                             _Float16* __restrict__ vT,
                                             _Float16* __restrict__ Wt16,
                                             _Float16* __restrict__ Wtlo) {
    __shared__ _Float16 bs[64 * LDB];   // 17408 B
    const int bb = blockIdx.y, s0 = blockIdx.x * 64;
    const int tid = threadIdx.x;

    // W fold-in: the 8 blocks with blockIdx.x==0 each convert 1/8 of W (2048 elems)
    if (blockIdx.x == 0) {
        int base = bb * 2048 + tid * 8;
        #pragma unroll
        for (int j = 0; j < 8; ++j) {
            int i = base + j;
            int d = i >> 7, e = i & 127;
            float w = W[i];                    // W[d][e]
            _Float16 hi = (_Float16)w;
            Wt16[e * 128 + d] = hi;
            Wtlo[e * 128 + d] = (_Float16)(w - (float)hi);
        }
    }

    const float* bg = b + ((size_t)bb * SE + s0) * D_;
    _Float16* kg = kc + ((size_t)bb * SE + s0) * D_;
    #pragma unroll
    for (int it = 0; it < 4; ++it) {
        int idx = tid + it * 256;
        int row = idx >> 4, seg = idx & 15;
        const float* src = bg + row * D_ + seg * 8;
        float4 a = *(const float4*)src;
        float4 c = *(const float4*)(src + 4);
        half8 hv;
        hv[0] = (_Float16)a.x; hv[1] = (_Float16)a.y; hv[2] = (_Float16)a.z; hv[3] = (_Float16)a.w;
        hv[4] = (_Float16)c.x; hv[5] = (_Float16)c.y; hv[6] = (_Float16)c.z; hv[7] = (_Float16)c.w;
        *(half8*)(kg + row * D_ + seg * 8) = hv;       // coalesced fp16 K image
        *(half8*)(bs + row * LDB + seg * 8) = hv;      // stage for transpose
    }
    __syncthreads();

    // transpose: each thread does an 8s x 4d micro-tile -> 16B s-contiguous stores
    const int sg = tid & 7, dg = tid >> 3;             // s = sg*8..+7, d = dg*4..+3
    half4 rowv[8];
    #pragma unroll
    for (int j = 0; j < 8; ++j)
        rowv[j] = *(const half4*)(bs + (sg * 8 + j) * LDB + dg * 4);
    #pragma unroll
    for (int dd = 0; dd < 4; ++dd) {
        half8 o;
        #pragma unroll
        for (int j = 0; j < 8; ++j) o[j] = rowv[j][dd];
        *(half8*)(vT + ((size_t)bb * D_ + dg * 4 + dd) * SE + s0 + sg * 8) = o;
    }
}

// ---------- fused flash attention, s-split ----------
// 512 threads = 8 waves = 4 wq (32 q rows each, 2 Q-frags) x 2 ws (32 s per tile).
// blockIdx.z in {0,1} selects the encoder half (2048 s = 32 tiles). Per CU: LDS-read
// cycles HALVE vs round 3 (each block covers 128 q on the same K/V reads) while
// occupancy stays 2 blocks/CU = 4 waves/SIMD. Each z-half writes unnormalized O +
// (m,l); a tiny merge kernel combines exactly.
__global__ __launch_bounds__(512, 4) void flash(const float* __restrict__ h,
                                                const _Float16* __restrict__ Wt16,
                                                const _Float16* __restrict__ Wtlo,
                                                const _Float16* __restrict__ kc,
                                                const _Float16* __restrict__ vT,
                                                float* __restrict__ out,
                                                float* __restrict__ P1,
                                                float2* __restrict__ mlA,
                                                float2* __restrict__ mlB) {
    __shared__ _Float16 KV[2][16384];   // per buf: K image 8192 halves + V image 8192

    const int bb   = blockIdx.y;
    const int q0   = blockIdx.x * 128;
    const int z    = blockIdx.z;
    const int tid  = threadIdx.x;      // 0..511
    const int wave = tid >> 6;         // 0..7
    const int wq   = wave >> 1;        // q-group 0..3 (32 q rows each)
    const int ws   = wave & 1;         // s-group 0..1 (32 s each per tile)
    const int lane = tid & 63;
    const int l15  = lane & 15;
    const int quad = lane >> 4;

    const _Float16* kbase = kc + (size_t)bb * SE * D_ + (size_t)z * (SE / NZ) * D_;
    const _Float16* vbase = vT + (size_t)bb * D_ * SE + (size_t)z * (SE / NZ);

    // per-lane DMA gather offsets; 1024 chunks per image, 2 rounds of 512 threads.
    // K rows permuted so lane P values are s-contiguous (x32 PV A-frag).
    int koff[2], voff[2];
    #pragma unroll
    for (int it = 0; it < 2; ++it) {
        int i = it * 512 + wave * 64 + lane;      // linear 16B chunk index in image
        int kr = i >> 4, kpp = i & 15;            // K: 64 rows x 16 chunks
        int km = kr & 15;
        int srow = (kr & 32) + ((km >> 2) << 3) + (((kr >> 4) & 1) << 2) + (km & 3);
        koff[it] = srow * D_ + ((kpp ^ km) * 8);
        int vr = i >> 3, vpp = i & 7;             // V: 128 rows x 8 chunks (linear rows)
        voff[it] = vr * SE + ((vpp ^ (vr & 7)) * 8);
    }

    // hoisted LDS read bases
    const _Float16* kA0[4]; const _Float16* kA1[4];
    const _Float16 *vB0, *vB1;
    #pragma unroll
    for (int ks = 0; ks < 4; ++ks) {
        int o = l15 * 128 + (((ks * 4 + quad) ^ l15) * 8) + ws * 4096;
        kA0[ks] = &KV[0][o]; kA1[ks] = &KV[1][o];
    }
    {
        int o = 8192 + l15 * 64 + (((ws * 4 + quad) ^ (l15 & 7)) * 8);
        vB0 = &KV[0][o]; vB1 = &KV[1][o];
    }

    // issue tile 0 DMA into KV[0]; prologue below only touches KV[1] -> full overlap
    {
        _Float16* buf0 = &KV[0][0];
        #pragma unroll
        for (int it = 0; it < 2; ++it) {
            cp16_async(kbase + koff[it], buf0 + (it * 512 + wave * 64) * 8);
            cp16_async(vbase + voff[it], buf0 + 8192 + (it * 512 + wave * 64) * 8);
        }
    }

    // ---- prologue: q' = (h @ W) * log2e for 128 rows, 2-stage via KV[1] scratch ----
    // Wave w computes C for global q rows 16w..16w+15 (all 128 d), then rows are
    // redistributed via the same scratch so wave (wq,ws) loads frags for rows
    // wq*32 + qq*16 (qq = 0,1).
    _Float16* hs = &KV[1][0];          // 64 x LDB = 8704 halves < 16384
    const float* hg = h + ((size_t)bb * SD + q0) * D_;
    half8 af[4];
    {
        // stage A: rows 0..63
        #pragma unroll
        for (int it = 0; it < 2; ++it) {
            int idx = tid + it * 512;
            int row = idx >> 4, seg = idx & 15;
            const float* src = hg + row * D_ + seg * 8;
            float4 a = *(const float4*)src;
            float4 c = *(const float4*)(src + 4);
            half8 hv;
            hv[0] = (_Float16)a.x; hv[1] = (_Float16)a.y; hv[2] = (_Float16)a.z; hv[3] = (_Float16)a.w;
            hv[4] = (_Float16)c.x; hv[5] = (_Float16)c.y; hv[6] = (_Float16)c.z; hv[7] = (_Float16)c.w;
            *(half8*)(hs + row * LDB + seg * 8) = hv;
        }
        __syncthreads();
        if (wave < 4) {
            #pragma unroll
            for (int ks = 0; ks < 4; ++ks)
                af[ks] = *(const half8*)(hs + (wave * 16 + l15) * LDB + ks * 32 + quad * 8);
        }
        __syncthreads();
        // stage B: rows 64..127
        #pragma unroll
        for (int it = 0; it < 2; ++it) {
            int idx = tid + it * 512;
            int row = idx >> 4, seg = idx & 15;
            const float* src = hg + (row + 64) * D_ + seg * 8;
            float4 a = *(const float4*)src;
            float4 c = *(const float4*)(src + 4);
            half8 hv;
            hv[0] = (_Float16)a.x; hv[1] = (_Float16)a.y; hv[2] = (_Float16)a.z; hv[3] = (_Float16)a.w;
            hv[4] = (_Float16)c.x; hv[5] = (_Float16)c.y; hv[6] = (_Float16)c.z; hv[7] = (_Float16)c.w;
            *(half8*)(hs + row * LDB + seg * 8) = hv;
        }
        __syncthreads();
        if (wave >= 4) {
            #pragma unroll
            for (int ks = 0; ks < 4; ++ks)
                af[ks] = *(const half8*)(hs + ((wave - 4) * 16 + l15) * LDB + ks * 32 + quad * 8);
        }
        __syncthreads();   // all hs reads done before C-writes below
    }
    half8 qf0[4], qf1[4];
    {
        floatx4 acc[8];
        #pragma unroll
        for (int nt = 0; nt < 8; ++nt) acc[nt] = (floatx4){0.f, 0.f, 0.f, 0.f};
        #pragma unroll
        for (int ks = 0; ks < 4; ++ks) {
            #pragma unroll
            for (int nt = 0; nt < 8; ++nt) {
                size_t wo = (size_t)(nt * 16 + l15) * 128 + ks * 32 + quad * 8;
                half8 bh = *(const half8*)(Wt16 + wo);
                half8 bl = *(const half8*)(Wtlo + wo);
                acc[nt] = __builtin_amdgcn_mfma_f32_16x16x32_f16(af[ks], bh, acc[nt], 0, 0, 0);
                acc[nt] = __builtin_amdgcn_mfma_f32_16x16x32_f16(af[ks], bl, acc[nt], 0, 0, 0);
            }
        }
        // redistribute rows 0..63 (waves 0-3), then rows 64..127 (waves 4-7)
        if (wave < 4) {
            #pragma unroll
            for (int nt = 0; nt < 8; ++nt)
                #pragma unroll
                for (int r = 0; r < 4; ++r)
                    hs[(wave * 16 + quad * 4 + r) * LDB + nt * 16 + l15] =
                        (_Float16)(acc[nt][r] * LOG2E);
        }
        __syncthreads();
        if (wq < 2) {
            #pragma unroll
            for (int ks = 0; ks < 4; ++ks) {
                qf0[ks] = *(const half8*)(hs + (wq * 32 + l15) * LDB + ks * 32 + quad * 8);
                qf1[ks] = *(const half8*)(hs + (wq * 32 + 16 + l15) * LDB + ks * 32 + quad * 8);
            }
        }
        __syncthreads();
        if (wave >= 4) {
            #pragma unroll
            for (int nt = 0; nt < 8; ++nt)
                #pragma unroll
                for (int r = 0; r < 4; ++r)
                    hs[((wave - 4) * 16 + quad * 4 + r) * LDB + nt * 16 + l15] =
                        (_Float16)(acc[nt][r] * LOG2E);
        }
        __syncthreads();
        if (wq >= 2) {
            #pragma unroll
            for (int ks = 0; ks < 4; ++ks) {
                qf0[ks] = *(const half8*)(hs + ((wq - 2) * 32 + l15) * LDB + ks * 32 + quad * 8);
                qf1[ks] = *(const half8*)(hs + ((wq - 2) * 32 + 16 + l15) * LDB + ks * 32 + quad * 8);
            }
        }
        // STEP(0)'s top barrier orders these reads vs tile-1 DMA into KV[1]
    }

    floatx4 acc_o0[8], acc_o1[8];
    #pragma unroll
    for (int dt = 0; dt < 8; ++dt) {
        acc_o0[dt] = (floatx4){0.f, 0.f, 0.f, 0.f};
        acc_o1[dt] = (floatx4){0.f, 0.f, 0.f, 0.f};
    }
    float nm0 = 0.f, nm1 = 0.f;        // -(running max, base-2), per q-frag
    float lp0 = 0.f, lp1 = 0.f;        // per-lane partial denominators
    const half2v one2 = { (_Float16)1.f, (_Float16)1.f };

#define RESCALE(MV, NM, LP, ACCS, ACCO)                                               \
    { float mr = fmaxf((MV), __shfl_xor((MV), 16, 64));                               \
      mr = fmaxf(mr, __shfl_xor(mr, 32, 64));                                         \
      float delta = fmaxf(mr, 0.f);                                                   \
      float alpha = exp2f(-delta);                                                    \
      LP *= alpha;                                                                    \
      float ab[4];                                                                    \
      _Pragma("unroll")                                                               \
      for (int r = 0; r < 4; ++r) ab[r] = __shfl(alpha, quad * 4 + r, 64);            \
      _Pragma("unroll")                                                               \
      for (int dt = 0; dt < 8; ++dt)                                                  \
        _Pragma("unroll")                                                             \
        for (int r = 0; r < 4; ++r) ACCO[dt][r] *= ab[r];                             \
      _Pragma("unroll")                                                               \
      for (int stl = 0; stl < 2; ++stl)                                               \
        _Pragma("unroll")                                                             \
        for (int r = 0; r < 4; ++r) ACCS[stl][r] -= delta;                            \
      NM -= delta; }

#define SOFTPACK(ACCS, LP, PA)                                                        \
    { float p0 = exp2f(ACCS[0][0]), p1 = exp2f(ACCS[0][1]);                           \
      float p2 = exp2f(ACCS[0][2]), p3 = exp2f(ACCS[0][3]);                           \
      float p4 = exp2f(ACCS[1][0]), p5 = exp2f(ACCS[1][1]);                           \
      float p6 = exp2f(ACCS[1][2]), p7 = exp2f(ACCS[1][3]);                           \
      half2v c0 = __builtin_bit_cast(half2v, __builtin_amdgcn_cvt_pkrtz(p0, p1));     \
      half2v c1 = __builtin_bit_cast(half2v, __builtin_amdgcn_cvt_pkrtz(p2, p3));     \
      half2v c2 = __builtin_bit_cast(half2v, __builtin_amdgcn_cvt_pkrtz(p4, p5));     \
      half2v c3 = __builtin_bit_cast(half2v, __builtin_amdgcn_cvt_pkrtz(p6, p7));     \
      LP = dot2acc(c0, one2, LP);                                                     \
      LP = dot2acc(c1, one2, LP);                                                     \
      LP = dot2acc(c2, one2, LP);                                                     \
      LP = dot2acc(c3, one2, LP);                                                     \
      PA[0] = c0[0]; PA[1] = c0[1]; PA[2] = c1[0]; PA[3] = c1[1];                     \
      PA[4] = c2[0]; PA[5] = c2[1]; PA[6] = c3[0]; PA[7] = c3[1]; }

// one tile step: compute from (KA,VBP), prefetch tile T+1 into NBUF
#define STEP(T, KA, VBP, NBUF)                                                        \
  {                                                                                   \
    __syncthreads();   /* vmcnt drain -> tile T landed for all waves */               \
    if ((T) + 1 < TILES) {                                                            \
      const _Float16* kt = kbase + (size_t)((T) + 1) * (NT * D_);                     \
      const _Float16* vt = vbase + (size_t)((T) + 1) * NT;                            \
      _Float16* bufn = (NBUF);                                                        \
      _Pragma("unroll")                                                               \
      for (int it = 0; it < 2; ++it) {                                                \
        cp16_async(kt + koff[it], bufn + (it * 512 + wave * 64) * 8);                 \
        cp16_async(vt + voff[it], bufn + 8192 + (it * 512 + wave * 64) * 8);          \
      }                                                                               \
    }                                                                                 \
    floatx4 accs0[2], accs1[2];                                                       \
    accs0[0] = (floatx4){nm0, nm0, nm0, nm0}; accs0[1] = accs0[0];                    \
    accs1[0] = (floatx4){nm1, nm1, nm1, nm1}; accs1[1] = accs1[0];                    \
    _Pragma("unroll")                                                                 \
    for (int ks = 0; ks < 4; ++ks) {                                                  \
      half8 af0 = *(const half8*)(KA[ks]);                                            \
      half8 af1 = *(const half8*)(KA[ks] + 2048);                                     \
      accs0[0] = __builtin_amdgcn_mfma_f32_16x16x32_f16(af0, qf0[ks], accs0[0], 0, 0, 0); \
      accs0[1] = __builtin_amdgcn_mfma_f32_16x16x32_f16(af1, qf0[ks], accs0[1], 0, 0, 0); \
      accs1[0] = __builtin_amdgcn_mfma_f32_16x16x32_f16(af0, qf1[ks], accs1[0], 0, 0, 0); \
      accs1[1] = __builtin_amdgcn_mfma_f32_16x16x32_f16(af1, qf1[ks], accs1[1], 0, 0, 0); \
    }                                                                                 \
    float mv0 = fmaxf(fmaxf(fmaxf(accs0[0][0], accs0[0][1]), fmaxf(accs0[0][2], accs0[0][3])), \
                      fmaxf(fmaxf(accs0[1][0], accs0[1][1]), fmaxf(accs0[1][2], accs0[1][3]))); \
    float mv1 = fmaxf(fmaxf(fmaxf(accs1[0][0], accs1[0][1]), fmaxf(accs1[0][2], accs1[0][3])), \
                      fmaxf(fmaxf(accs1[1][0], accs1[1][1]), fmaxf(accs1[1][2], accs1[1][3]))); \
    if (__ballot((mv0 > 11.5f) || (mv1 > 11.5f)) != 0ull) {                           \
      RESCALE(mv0, nm0, lp0, accs0, acc_o0);                                          \
      RESCALE(mv1, nm1, lp1, accs1, acc_o1);                                          \
    }                                                                                 \
    half8 pA0, pA1;                                                                   \
    SOFTPACK(accs0, lp0, pA0);                                                        \
    SOFTPACK(accs1, lp1, pA1);                                                        \
    _Pragma("unroll")                                                                 \
    for (int dt = 0; dt < 8; ++dt) {                                                  \
      half8 vf = *(const half8*)((VBP) + dt * 1024);                                  \
      acc_o0[dt] = __builtin_amdgcn_mfma_f32_16x16x32_f16(pA0, vf, acc_o0[dt], 0, 0, 0); \
      acc_o1[dt] = __builtin_amdgcn_mfma_f32_16x16x32_f16(pA1, vf, acc_o1[dt], 0, 0, 0); \
    }                                                                                 \
  }

    for (int t = 0; t < TILES; t += 2) {
        STEP(t,     kA0, vB0, &KV[1][0]);
        STEP(t + 1, kA1, vB1, &KV[0][0]);
    }
#undef STEP

    // ---- epilogue: cross-ws merge (exact), write UNNORMALIZED O + (m,l) ----
    const float m_q0 = -nm0, m_q1 = -nm1;
    float lo0, lo1;
    {
        float l = lp0;
        l += __shfl_xor(l, 16, 64);
        l += __shfl_xor(l, 32, 64);
        lo0 = l;
        l = lp1;
        l += __shfl_xor(l, 16, 64);
        l += __shfl_xor(l, 32, 64);
        lo1 = l;
    }

    __syncthreads();                   // all PV reads of KV done; safe to overwrite
    float*  Ob  = (float*)&KV[0][0];   // [wq][dt][lane] float4 : 32 KB (one q-frag)
    float2* mlb = (float2*)&KV[1][0];  // ws1 m,l pairs: [wq*32 + qq*16 + q] (128)

    float* dstO = (z == 0) ? out : P1;
    float2* dstml = (z == 0) ? mlA : mlB;

    if (ws == 1) {
        #pragma unroll
        for (int dt = 0; dt < 8; ++dt)
            *(floatx4*)(Ob + ((wq * 8 + dt) * 64 + lane) * 4) = acc_o0[dt];
        if (quad == 0) {
            mlb[wq * 32 + l15]      = make_float2(m_q0, lo0);
            mlb[wq * 32 + 16 + l15] = make_float2(m_q1, lo1);
        }
    }
    __syncthreads();

#define COMBINE(ACC, MQ, LO, QQ)                                                      \
    { float m0r[4], l0r[4], m1r[4], l1r[4];                                           \
      _Pragma("unroll")                                                               \
      for (int r = 0; r < 4; ++r) {                                                   \
          m0r[r] = __shfl((MQ), quad * 4 + r, 64);                                    \
          l0r[r] = __shfl((LO), quad * 4 + r, 64);                                    \
          float2 p = mlb[wq * 32 + (QQ) * 16 + quad * 4 + r];                         \
          m1r[r] = p.x; l1r[r] = p.y;                                                 \
      }                                                                               \
      float a0[4], a1[4], mm[4], lc[4];                                               \
      _Pragma("unroll")                                                               \
      for (int r = 0; r < 4; ++r) {                                                   \
          mm[r] = fmaxf(m0r[r], m1r[r]);                                              \
          a0[r] = exp2f(m0r[r] - mm[r]);                                              \
          a1[r] = exp2f(m1r[r] - mm[r]);                                              \
          lc[r] = l0r[r] * a0[r] + l1r[r] * a1[r];                                    \
      }                                                                               \
      size_t qrow = (size_t)bb * SD + q0 + wq * 32 + (QQ) * 16 + quad * 4;            \
      float* orow = dstO + qrow * D_;                                                 \
      _Pragma("unroll")                                                               \
      for (int dt = 0; dt < 8; ++dt) {                                                \
          floatx4 o1 = *(floatx4*)(Ob + ((wq * 8 + dt) * 64 + lane) * 4);             \
          _Pragma("unroll")                                                           \
          for (int r = 0; r < 4; ++r)                                                 \
              orow[(size_t)r * D_ + dt * 16 + l15] =                                  \
                  ACC[dt][r] * a0[r] + o1[r] * a1[r];                                 \
      }                                                                               \
      if (l15 == 0) {                                                                 \
          _Pragma("unroll")                                                           \
          for (int r = 0; r < 4; ++r) dstml[qrow + r] = make_float2(mm[r], lc[r]);    \
      } }

    if (ws == 0) COMBINE(acc_o0, m_q0, lo0, 0);
    __syncthreads();                   // qq0 combine reads done before overwrite
    if (ws == 1) {
        #pragma unroll
        for (int dt = 0; dt < 8; ++dt)
            *(floatx4*)(Ob + ((wq * 8 + dt) * 64 + lane) * 4) = acc_o1[dt];
    }
    __syncthreads();
    if (ws == 0) COMBINE(acc_o1, m_q1, lo1, 1);
#undef COMBINE
#undef RESCALE
#undef SOFTPACK
}

// ---------- merge: out = normalize(combine(out_raw, P1_raw)) ----------
__global__ __launch_bounds__(256) void merge(float* __restrict__ out,
                                             const float* __restrict__ P1,
                                             const float2* __restrict__ mlA,
                                             const float2* __restrict__ mlB) {
    int idx = blockIdx.x * 256 + threadIdx.x;   // grid 16384 -> B*SD*D/4 float4s
    int row = idx >> 5;                          // 32 float4 per 128-d row
    float2 A = mlA[row], Bp = mlB[row];
    float mm = fmaxf(A.x, Bp.x);
    float a0 = exp2f(A.x - mm), a1 = exp2f(Bp.x - mm);
    float inv = 1.f / (A.y * a0 + Bp.y * a1);
    float4 o0 = ((const float4*)out)[idx];
    float4 o1 = ((const float4*)P1)[idx];
    float4 rlt;
    rlt.x = (o0.x * a0 + o1.x * a1) * inv;
    rlt.y = (o0.y * a0 + o1.y * a1) * inv;
    rlt.z = (o0.z * a0 + o1.z * a1) * inv;
    rlt.w = (o0.w * a0 + o1.w * a1) * inv;
    ((float4*)out)[idx] = rlt;
}

extern "C" void kernel_launch(void* const* d_in, const int* in_sizes, int n_in,
                              void* d_out, int out_size, void* d_ws, size_t ws_size,
                              hipStream_t stream) {
    const float* b = (const float*)d_in[0];   // [B, SE, D]
    const float* h = (const float*)d_in[1];   // [B, SD, D]
    const float* W = (const float*)d_in[2];   // [D, D]
    float* out = (float*)d_out;               // [B, SD, D] fp32

    _Float16* Wt16 = (_Float16*)d_ws;                      // 32 KB
    _Float16* Wtlo = Wt16 + 128 * 128;                     // 32 KB
    _Float16* kc   = Wtlo + 128 * 128;                     // [B, SE, D] fp16 (64 MB)
    _Float16* vT   = kc + (size_t)B_ * SE * D_;            // [B, D, SE] fp16 (64 MB)
    float*    P1   = (float*)(vT + (size_t)B_ * D_ * SE);  // [B, SD, D] fp32 (16 MB)
    float2*   mlA  = (float2*)(P1 + (size_t)B_ * SD * D_); // [B*SD] (256 KB)
    float2*   mlB  = mlA + (size_t)B_ * SD;                // [B*SD] (256 KB)

    bprep<<<dim3(SE / 64, B_), 256, 0, stream>>>(b, W, kc, vT, Wt16, Wtlo);
    flash<<<dim3(SD / 128, B_, NZ), 512, 0, stream>>>(h, Wt16, Wtlo, kc, vT,
                                                      out, P1, mlA, mlB);
    merge<<<(B_ * SD * D_ / 4) / 256, 256, 0, stream>>>(out, P1, mlA, mlB);
}